// Round 1
// baseline (276.625 us; speedup 1.0000x reference)
//
#include <hip/hip_runtime.h>
#include <cmath>
#include <complex>
#include <algorithm>
#include <vector>

#define NEDGES 16384
#define INDIM  240
#define SHDIM  9
#define OUTDIM 240
#define WNUM   13824

// Flat concatenated (pw-scaled) real Wigner-3j tensors for the 11 paths.
// Offsets: p0:0(1) p1:1(9) p2:10(25) p3:35(9) p4:44(9) p5:53(45)
//          p6:98(45) p7:143(25) p8:168(45) p9:213(25) p10:238(125)  total 363
struct TPConsts { float C[363]; };

// ---------------- host: exact transliteration of the reference ----------------
static double factd(int n){ double r=1.0; for(int i=2;i<=n;++i) r*= (double)i; return r; }

static double su2_cg_coeff(int j1,int m1,int j2,int m2,int j3,int m3){
    if(m3 != m1+m2) return 0.0;
    int vmin = std::max(std::max(-j1+j2+m3, -j1+m1), 0);
    int vmax = std::min(std::min(j2+j3+m1, j3-j1+j2), j3+m3);
    double C = std::sqrt((double)(2*j3+1)*factd(j3+j1-j2)*factd(j3-j1+j2)*factd(j1+j2-j3)
               *factd(j3+m3)*factd(j3-m3)
               /(factd(j1+j2+j3+1)*factd(j1-m1)*factd(j1+m1)*factd(j2-m2)*factd(j2+m2)));
    double S=0.0;
    for(int v=vmin; v<=vmax; ++v){
        double sgn = ((v+j2+m2)&1) ? -1.0 : 1.0;
        S += sgn * factd(j2+j3+m1-v)*factd(j1-m1+v)
             /(factd(v)*factd(j3-j1+j2-v)*factd(j3+m3-v)*factd(v+j1-j2-m3));
    }
    return C*S;
}

static void real_to_complex(int l, std::complex<double>* q){
    int d=2*l+1;
    for(int i=0;i<d*d;++i) q[i]=std::complex<double>(0,0);
    const double s = 1.0/std::sqrt(2.0);
    const std::complex<double> I(0.0,1.0);
    for(int m=-l;m<=-1;++m){
        q[(l+m)*d + (l-m)] = s;        // col l+|m|
        q[(l+m)*d + (l+m)] = -I*s;     // col l-|m|
    }
    q[l*d+l]=1.0;
    for(int m=1;m<=l;++m){
        double sg = (m&1) ? -1.0 : 1.0;
        q[(l+m)*d + (l+m)] = sg*s;
        q[(l+m)*d + (l-m)] = I*sg*s;
    }
    std::complex<double> ph(1.0,0.0);
    for(int t=0;t<l;++t) ph *= std::complex<double>(0.0,-1.0);  // (-i)^l
    for(int i=0;i<d*d;++i) q[i]*=ph;
}

static void wigner3j(int l1,int l2,int l3, float* out, double scale){
    int d1=2*l1+1, d2=2*l2+1, d3=2*l3+1;
    std::vector<double> cg((size_t)d1*d2*d3, 0.0);
    for(int m1=-l1;m1<=l1;++m1)
        for(int m2=-l2;m2<=l2;++m2){
            int m3=m1+m2;
            if(std::abs(m3)<=l3)
                cg[((size_t)(l1+m1)*d2 + (l2+m2))*d3 + (l3+m3)] = su2_cg_coeff(l1,m1,l2,m2,l3,m3);
        }
    std::vector<std::complex<double>> Q1((size_t)d1*d1), Q2((size_t)d2*d2), Q3((size_t)d3*d3);
    real_to_complex(l1,Q1.data());
    real_to_complex(l2,Q2.data());
    real_to_complex(l3,Q3.data());
    std::vector<double> Cr((size_t)d1*d2*d3, 0.0);
    // out[j,l,m] = Re sum_{i,k,n} Q1[i,j] Q2[k,l] conj(Q3[m,n]) cg[i,k,n]
    for(int j=0;j<d1;++j) for(int l=0;l<d2;++l) for(int m=0;m<d3;++m){
        std::complex<double> s(0,0);
        for(int i=0;i<d1;++i) for(int k=0;k<d2;++k) for(int n=0;n<d3;++n){
            double c = cg[((size_t)i*d2+k)*d3+n];
            if(c!=0.0) s += Q1[(size_t)i*d1+j]*Q2[(size_t)k*d2+l]*std::conj(Q3[(size_t)m*d3+n])*c;
        }
        Cr[((size_t)j*d2+l)*d3+m] = s.real();
    }
    double nrm=0.0; for(double x: Cr) nrm += x*x; nrm = std::sqrt(nrm);
    for(size_t i=0;i<Cr.size();++i) out[i] = (float)(Cr[i]/nrm*scale);
}

static void build_consts(TPConsts* cc){
    const double pw0 = std::sqrt(1.0/112.0);   // i3=0
    const double pw1 = std::sqrt(3.0/144.0);   // i3=1
    const double pw2 = std::sqrt(5.0/128.0);   // i3=2
    wigner3j(0,0,0, cc->C+0,   pw0);
    wigner3j(0,1,1, cc->C+1,   pw1);
    wigner3j(0,2,2, cc->C+10,  pw2);
    wigner3j(1,0,1, cc->C+35,  pw1);
    wigner3j(1,1,0, cc->C+44,  pw0);
    wigner3j(1,1,2, cc->C+53,  pw2);
    wigner3j(1,2,1, cc->C+98,  pw1);
    wigner3j(2,0,2, cc->C+143, pw2);
    wigner3j(2,1,1, cc->C+168, pw1);
    wigner3j(2,2,0, cc->C+213, pw0);
    wigner3j(2,2,2, cc->C+238, pw2);
}

// ---------------- device ----------------
// A-phase: A[u,k] = sum_i u1[u,i] * (sum_j C[i,j,k] v[j])
template<int L1,int L2,int L3,int MUL1>
__device__ __forceinline__ void compute_A(const float* __restrict__ Cp,
        const float* __restrict__ urow, const float* __restrict__ vrow,
        float* __restrict__ As, int worker){
    constexpr int D1=2*L1+1, D2=2*L2+1, K=2*L3+1;
    float vv[D2];
    #pragma unroll
    for(int j=0;j<D2;++j) vv[j]=vrow[j];
    float B[D1][K];
    #pragma unroll
    for(int i=0;i<D1;++i){
        #pragma unroll
        for(int k=0;k<K;++k){
            float b=0.f;
            #pragma unroll
            for(int j=0;j<D2;++j) b = fmaf(Cp[(i*D2+j)*K+k], vv[j], b);
            B[i][k]=b;
        }
    }
    constexpr int N = MUL1*K;
    #pragma unroll 1
    for(int e=worker; e<N; e+=32){
        int uu = e/K, k = e - uu*K;
        float a=0.f;
        #pragma unroll
        for(int i=0;i<D1;++i) a = fmaf(urow[uu*D1+i], B[i][k], a);
        As[e]=a;
    }
}

// main streaming contraction: acc[c][k] += W[u, wq*4+c] * A[u,k]
template<int MUL1,int MUL3,int K>
__device__ __forceinline__ void accum_path(const float* __restrict__ wseg,
        const float* __restrict__ As, int wq, float (&acc)[4][K]){
    #pragma unroll 4
    for(int u=0;u<MUL1;++u){
        const float4 wv = *reinterpret_cast<const float4*>(wseg + u*MUL3 + wq*4);
        #pragma unroll
        for(int k=0;k<K;++k){
            float a = As[u*K+k];
            acc[0][k] = fmaf(wv.x, a, acc[0][k]);
            acc[1][k] = fmaf(wv.y, a, acc[1][k]);
            acc[2][k] = fmaf(wv.z, a, acc[2][k]);
            acc[3][k] = fmaf(wv.w, a, acc[3][k]);
        }
    }
}

__global__ __launch_bounds__(256)
void tp_kernel(const float* __restrict__ U, const float* __restrict__ V,
               const float* __restrict__ W, float* __restrict__ Out, TPConsts cc){
    __shared__ float As[8*1184];
    const int tid = threadIdx.x, blk = blockIdx.x;

    // ---- A-phase: 32 workers per edge, 8 edges per block ----
    {
        const int el = tid>>5, worker = tid&31;
        const int z  = blk*8 + el;
        const float* urow = U + (size_t)z*INDIM;
        const float* vrow = V + (size_t)z*SHDIM;
        float* A = As + el*1184;
        compute_A<0,0,0,64>(cc.C+0,   urow,     vrow,   A+0,    worker);
        compute_A<0,1,1,64>(cc.C+1,   urow,     vrow+1, A+64,   worker);
        compute_A<0,2,2,64>(cc.C+10,  urow,     vrow+4, A+256,  worker);
        compute_A<1,0,1,32>(cc.C+35,  urow+64,  vrow,   A+576,  worker);
        compute_A<1,1,0,32>(cc.C+44,  urow+64,  vrow+1, A+672,  worker);
        compute_A<1,1,2,32>(cc.C+53,  urow+64,  vrow+1, A+704,  worker);
        compute_A<1,2,1,32>(cc.C+98,  urow+64,  vrow+4, A+864,  worker);
        compute_A<2,0,2,16>(cc.C+143, urow+160, vrow,   A+960,  worker);
        compute_A<2,1,1,16>(cc.C+168, urow+160, vrow+1, A+1040, worker);
        compute_A<2,2,0,16>(cc.C+213, urow+160, vrow+4, A+1088, worker);
        compute_A<2,2,2,16>(cc.C+238, urow+160, vrow+4, A+1104, worker);
    }
    __syncthreads();

    // ---- main: lane owns one output quad-column of one edge ----
    const int lane = tid&63, wave = tid>>6;
    const int e2 = lane>>5, col = lane&31;
    const int el = wave*2 + e2;
    const int z  = blk*8 + el;
    const float* wrow = W + (size_t)z*WNUM;
    const float* A    = As + el*1184;
    float* orow = Out + (size_t)z*OUTDIM;

    if(col < 16){                 // i3=0 (l3=0), 64 outputs -> 16 quads
        const int wq = col;
        float acc[4][1] = {};
        accum_path<64,64,1>(wrow+0,     A+0,    wq, acc);
        accum_path<32,64,1>(wrow+8192,  A+672,  wq, acc);
        accum_path<16,64,1>(wrow+12544, A+1088, wq, acc);
        float4 o; o.x=acc[0][0]; o.y=acc[1][0]; o.z=acc[2][0]; o.w=acc[3][0];
        *reinterpret_cast<float4*>(orow + wq*4) = o;
    } else if(col < 24){          // i3=1 (l3=1), 32 muls -> 8 quads
        const int wq = col-16;
        float acc[4][3] = {};
        accum_path<64,32,3>(wrow+4096,  A+64,   wq, acc);
        accum_path<32,32,3>(wrow+7168,  A+576,  wq, acc);
        accum_path<32,32,3>(wrow+10752, A+864,  wq, acc);
        accum_path<16,32,3>(wrow+12032, A+1040, wq, acc);
        #pragma unroll
        for(int c=0;c<4;++c)
            #pragma unroll
            for(int k=0;k<3;++k)
                orow[64 + (wq*4+c)*3 + k] = acc[c][k];
    } else if(col < 28){          // i3=2 (l3=2), 16 muls -> 4 quads
        const int wq = col-24;
        float acc[4][5] = {};
        accum_path<64,16,5>(wrow+6144,  A+256,  wq, acc);
        accum_path<32,16,5>(wrow+10240, A+704,  wq, acc);
        accum_path<16,16,5>(wrow+11776, A+960,  wq, acc);
        accum_path<16,16,5>(wrow+13568, A+1104, wq, acc);
        #pragma unroll
        for(int c=0;c<4;++c)
            #pragma unroll
            for(int k=0;k<5;++k)
                orow[160 + (wq*4+c)*5 + k] = acc[c][k];
    }
}

extern "C" void kernel_launch(void* const* d_in, const int* in_sizes, int n_in,
                              void* d_out, int out_size, void* d_ws, size_t ws_size,
                              hipStream_t stream) {
    (void)in_sizes; (void)n_in; (void)d_ws; (void)ws_size; (void)out_size;
    const float* u = (const float*)d_in[0];
    const float* v = (const float*)d_in[1];
    const float* w = (const float*)d_in[2];
    float* out = (float*)d_out;

    TPConsts cc;
    build_consts(&cc);

    tp_kernel<<<NEDGES/8, 256, 0, stream>>>(u, v, w, out, cc);
}

// Round 2
// 239.784 us; speedup vs baseline: 1.1536x; 1.1536x over previous
//
#include <hip/hip_runtime.h>
#include <cmath>
#include <complex>
#include <algorithm>
#include <vector>

#define NEDGES 16384
#define INDIM  240
#define SHDIM  9
#define OUTDIM 240
#define WNUM   13824

// Flat concatenated (pw-scaled) real Wigner-3j tensors for the 11 paths.
struct TPConsts { float C[363]; };

// ---------------- host: exact transliteration of the reference ----------------
static double factd(int n){ double r=1.0; for(int i=2;i<=n;++i) r*= (double)i; return r; }

static double su2_cg_coeff(int j1,int m1,int j2,int m2,int j3,int m3){
    if(m3 != m1+m2) return 0.0;
    int vmin = std::max(std::max(-j1+j2+m3, -j1+m1), 0);
    int vmax = std::min(std::min(j2+j3+m1, j3-j1+j2), j3+m3);
    double C = std::sqrt((double)(2*j3+1)*factd(j3+j1-j2)*factd(j3-j1+j2)*factd(j1+j2-j3)
               *factd(j3+m3)*factd(j3-m3)
               /(factd(j1+j2+j3+1)*factd(j1-m1)*factd(j1+m1)*factd(j2-m2)*factd(j2+m2)));
    double S=0.0;
    for(int v=vmin; v<=vmax; ++v){
        double sgn = ((v+j2+m2)&1) ? -1.0 : 1.0;
        S += sgn * factd(j2+j3+m1-v)*factd(j1-m1+v)
             /(factd(v)*factd(j3-j1+j2-v)*factd(j3+m3-v)*factd(v+j1-j2-m3));
    }
    return C*S;
}

static void real_to_complex(int l, std::complex<double>* q){
    int d=2*l+1;
    for(int i=0;i<d*d;++i) q[i]=std::complex<double>(0,0);
    const double s = 1.0/std::sqrt(2.0);
    const std::complex<double> I(0.0,1.0);
    for(int m=-l;m<=-1;++m){
        q[(l+m)*d + (l-m)] = s;
        q[(l+m)*d + (l+m)] = -I*s;
    }
    q[l*d+l]=1.0;
    for(int m=1;m<=l;++m){
        double sg = (m&1) ? -1.0 : 1.0;
        q[(l+m)*d + (l+m)] = sg*s;
        q[(l+m)*d + (l-m)] = I*sg*s;
    }
    std::complex<double> ph(1.0,0.0);
    for(int t=0;t<l;++t) ph *= std::complex<double>(0.0,-1.0);  // (-i)^l
    for(int i=0;i<d*d;++i) q[i]*=ph;
}

static void wigner3j(int l1,int l2,int l3, float* out, double scale){
    int d1=2*l1+1, d2=2*l2+1, d3=2*l3+1;
    std::vector<double> cg((size_t)d1*d2*d3, 0.0);
    for(int m1=-l1;m1<=l1;++m1)
        for(int m2=-l2;m2<=l2;++m2){
            int m3=m1+m2;
            if(std::abs(m3)<=l3)
                cg[((size_t)(l1+m1)*d2 + (l2+m2))*d3 + (l3+m3)] = su2_cg_coeff(l1,m1,l2,m2,l3,m3);
        }
    std::vector<std::complex<double>> Q1((size_t)d1*d1), Q2((size_t)d2*d2), Q3((size_t)d3*d3);
    real_to_complex(l1,Q1.data());
    real_to_complex(l2,Q2.data());
    real_to_complex(l3,Q3.data());
    std::vector<double> Cr((size_t)d1*d2*d3, 0.0);
    for(int j=0;j<d1;++j) for(int l=0;l<d2;++l) for(int m=0;m<d3;++m){
        std::complex<double> s(0,0);
        for(int i=0;i<d1;++i) for(int k=0;k<d2;++k) for(int n=0;n<d3;++n){
            double c = cg[((size_t)i*d2+k)*d3+n];
            if(c!=0.0) s += Q1[(size_t)i*d1+j]*Q2[(size_t)k*d2+l]*std::conj(Q3[(size_t)m*d3+n])*c;
        }
        Cr[((size_t)j*d2+l)*d3+m] = s.real();
    }
    double nrm=0.0; for(double x: Cr) nrm += x*x; nrm = std::sqrt(nrm);
    for(size_t i=0;i<Cr.size();++i) out[i] = (float)(Cr[i]/nrm*scale);
}

static void build_consts(TPConsts* cc){
    const double pw0 = std::sqrt(1.0/112.0);   // i3=0
    const double pw1 = std::sqrt(3.0/144.0);   // i3=1
    const double pw2 = std::sqrt(5.0/128.0);   // i3=2
    wigner3j(0,0,0, cc->C+0,   pw0);
    wigner3j(0,1,1, cc->C+1,   pw1);
    wigner3j(0,2,2, cc->C+10,  pw2);
    wigner3j(1,0,1, cc->C+35,  pw1);
    wigner3j(1,1,0, cc->C+44,  pw0);
    wigner3j(1,1,2, cc->C+53,  pw2);
    wigner3j(1,2,1, cc->C+98,  pw1);
    wigner3j(2,0,2, cc->C+143, pw2);
    wigner3j(2,1,1, cc->C+168, pw1);
    wigner3j(2,2,0, cc->C+213, pw0);
    wigner3j(2,2,2, cc->C+238, pw2);
}

// ---------------- device ----------------
// A-phase: A[u,k] = sum_i u1[u,i] * (sum_j C[i,j,k] v[j])
template<int L1,int L2,int L3,int MUL1>
__device__ __forceinline__ void compute_A(const float* __restrict__ Cp,
        const float* __restrict__ urow, const float* __restrict__ vrow,
        float* __restrict__ As, int worker){
    constexpr int D1=2*L1+1, D2=2*L2+1, K=2*L3+1;
    float vv[D2];
    #pragma unroll
    for(int j=0;j<D2;++j) vv[j]=vrow[j];
    float B[D1][K];
    #pragma unroll
    for(int i=0;i<D1;++i){
        #pragma unroll
        for(int k=0;k<K;++k){
            float b=0.f;
            #pragma unroll
            for(int j=0;j<D2;++j) b = fmaf(Cp[(i*D2+j)*K+k], vv[j], b);
            B[i][k]=b;
        }
    }
    constexpr int N = MUL1*K;
    #pragma unroll 1
    for(int e=worker; e<N; e+=32){
        int uu = e/K, k = e - uu*K;
        float a=0.f;
        #pragma unroll
        for(int i=0;i<D1;++i) a = fmaf(urow[uu*D1+i], B[i][k], a);
        As[e]=a;
    }
}

// streaming contraction: acc[c][k] += W[u, wq*4+c] * A[u,k]
template<int MUL1,int MUL3,int K>
__device__ __forceinline__ void accum_path(const float* __restrict__ wseg,
        const float* __restrict__ As, int wq, float (&acc)[4][K]){
    #pragma unroll 8
    for(int u=0;u<MUL1;++u){
        const float4 wv = *reinterpret_cast<const float4*>(wseg + u*MUL3 + wq*4);
        #pragma unroll
        for(int k=0;k<K;++k){
            float a = As[u*K+k];
            acc[0][k] = fmaf(wv.x, a, acc[0][k]);
            acc[1][k] = fmaf(wv.y, a, acc[1][k]);
            acc[2][k] = fmaf(wv.z, a, acc[2][k]);
            acc[3][k] = fmaf(wv.w, a, acc[3][k]);
        }
    }
}

__global__ __launch_bounds__(256)
void tp_kernel(const float* __restrict__ U, const float* __restrict__ V,
               const float* __restrict__ W, float* __restrict__ Out, TPConsts cc){
    __shared__ float As[8*1184];
    const int tid = threadIdx.x, blk = blockIdx.x;

    // ---- A-phase: 32 workers per edge, 8 edges per block ----
    {
        const int el = tid>>5, worker = tid&31;
        const int z  = blk*8 + el;
        const float* urow = U + (size_t)z*INDIM;
        const float* vrow = V + (size_t)z*SHDIM;
        float* A = As + el*1184;
        compute_A<0,0,0,64>(cc.C+0,   urow,     vrow,   A+0,    worker);
        compute_A<0,1,1,64>(cc.C+1,   urow,     vrow+1, A+64,   worker);
        compute_A<0,2,2,64>(cc.C+10,  urow,     vrow+4, A+256,  worker);
        compute_A<1,0,1,32>(cc.C+35,  urow+64,  vrow,   A+576,  worker);
        compute_A<1,1,0,32>(cc.C+44,  urow+64,  vrow+1, A+672,  worker);
        compute_A<1,1,2,32>(cc.C+53,  urow+64,  vrow+1, A+704,  worker);
        compute_A<1,2,1,32>(cc.C+98,  urow+64,  vrow+4, A+864,  worker);
        compute_A<2,0,2,16>(cc.C+143, urow+160, vrow,   A+960,  worker);
        compute_A<2,1,1,16>(cc.C+168, urow+160, vrow+1, A+1040, worker);
        compute_A<2,2,0,16>(cc.C+213, urow+160, vrow+4, A+1088, worker);
        compute_A<2,2,2,16>(cc.C+238, urow+160, vrow+4, A+1104, worker);
    }
    __syncthreads();

    // ---- main: wave-uniform path assignment (no intra-wave divergence) ----
    const int lane = tid&63, wave = tid>>6;

    if(wave < 2){
        // i3=0 (l3=0, 64 muls -> 16 quads). wave 0: edges 0-3, wave 1: edges 4-7
        const int el = wave*4 + (lane>>4);
        const int wq = lane&15;
        const int z  = blk*8 + el;
        const float* wrow = W + (size_t)z*WNUM;
        const float* A    = As + el*1184;
        float acc[4][1] = {};
        accum_path<64,64,1>(wrow+0,     A+0,    wq, acc);
        accum_path<32,64,1>(wrow+8192,  A+672,  wq, acc);
        accum_path<16,64,1>(wrow+12544, A+1088, wq, acc);
        float4 o; o.x=acc[0][0]; o.y=acc[1][0]; o.z=acc[2][0]; o.w=acc[3][0];
        *reinterpret_cast<float4*>(Out + (size_t)z*OUTDIM + wq*4) = o;
    } else if(wave == 2){
        // i3=1 (l3=1, 32 muls -> 8 quads), all 8 edges
        const int el = lane>>3;
        const int wq = lane&7;
        const int z  = blk*8 + el;
        const float* wrow = W + (size_t)z*WNUM;
        const float* A    = As + el*1184;
        float acc[4][3] = {};
        accum_path<64,32,3>(wrow+4096,  A+64,   wq, acc);
        accum_path<32,32,3>(wrow+7168,  A+576,  wq, acc);
        accum_path<32,32,3>(wrow+10752, A+864,  wq, acc);
        accum_path<16,32,3>(wrow+12032, A+1040, wq, acc);
        // 12 contiguous floats at Out + 64 + wq*12, order c*3+k
        float* o = Out + (size_t)z*OUTDIM + 64 + wq*12;
        float4 f0, f1, f2;
        f0.x=acc[0][0]; f0.y=acc[0][1]; f0.z=acc[0][2]; f0.w=acc[1][0];
        f1.x=acc[1][1]; f1.y=acc[1][2]; f1.z=acc[2][0]; f1.w=acc[2][1];
        f2.x=acc[2][2]; f2.y=acc[3][0]; f2.z=acc[3][1]; f2.w=acc[3][2];
        *reinterpret_cast<float4*>(o+0) = f0;
        *reinterpret_cast<float4*>(o+4) = f1;
        *reinterpret_cast<float4*>(o+8) = f2;
    } else {
        // i3=2 (l3=2, 16 muls -> 4 quads), all 8 edges; lanes split the u-range
        // lanes 0-31: first half of each path's u range; lanes 32-63: second half
        const int sub  = lane & 31;
        const int half = lane >> 5;
        const int el = sub>>2;
        const int wq = sub&3;
        const int z  = blk*8 + el;
        const float* wrow = W + (size_t)z*WNUM;
        const float* A    = As + el*1184;
        float acc[4][5] = {};
        // p2: i1=0 (MUL1=64), halves of 32
        accum_path<32,16,5>(wrow+6144  + half*32*16, A+256  + half*32*5, wq, acc);
        // p5: i1=1 (MUL1=32), halves of 16
        accum_path<16,16,5>(wrow+10240 + half*16*16, A+704  + half*16*5, wq, acc);
        // p7: i1=2 (MUL1=16), halves of 8
        accum_path<8,16,5>( wrow+11776 + half*8*16,  A+960  + half*8*5,  wq, acc);
        // p10: i1=2 (MUL1=16), halves of 8
        accum_path<8,16,5>( wrow+13568 + half*8*16,  A+1104 + half*8*5,  wq, acc);
        // combine halves: lane i += lane i+32
        #pragma unroll
        for(int c=0;c<4;++c)
            #pragma unroll
            for(int k=0;k<5;++k)
                acc[c][k] += __shfl_xor(acc[c][k], 32);
        if(half == 0){
            // 20 contiguous floats at Out + 160 + wq*20, order c*5+k
            float* o = Out + (size_t)z*OUTDIM + 160 + wq*20;
            float4 f0,f1,f2,f3;
            f0.x=acc[0][0]; f0.y=acc[0][1]; f0.z=acc[0][2]; f0.w=acc[0][3];
            f1.x=acc[0][4]; f1.y=acc[1][0]; f1.z=acc[1][1]; f1.w=acc[1][2];
            f2.x=acc[1][3]; f2.y=acc[1][4]; f2.z=acc[2][0]; f2.w=acc[2][1];
            f3.x=acc[2][2]; f3.y=acc[2][3]; f3.z=acc[2][4]; f3.w=acc[3][0];
            *reinterpret_cast<float4*>(o+0)  = f0;
            *reinterpret_cast<float4*>(o+4)  = f1;
            *reinterpret_cast<float4*>(o+8)  = f2;
            *reinterpret_cast<float4*>(o+12) = f3;
            o[16]=acc[3][1]; o[17]=acc[3][2]; o[18]=acc[3][3]; o[19]=acc[3][4];
        }
    }
}

extern "C" void kernel_launch(void* const* d_in, const int* in_sizes, int n_in,
                              void* d_out, int out_size, void* d_ws, size_t ws_size,
                              hipStream_t stream) {
    (void)in_sizes; (void)n_in; (void)d_ws; (void)ws_size; (void)out_size;
    const float* u = (const float*)d_in[0];
    const float* v = (const float*)d_in[1];
    const float* w = (const float*)d_in[2];
    float* out = (float*)d_out;

    TPConsts cc;
    build_consts(&cc);

    tp_kernel<<<NEDGES/8, 256, 0, stream>>>(u, v, w, out, cc);
}